// Round 11
// baseline (43.412 us; speedup 1.0000x reference)
//
#include <hip/hip_runtime.h>
#include <math.h>

#define V   50000
#define DIM 128
#define BB  512
#define LQ  30
#define RD  200
#define KN  21

typedef unsigned short ushort_t;
typedef __attribute__((ext_vector_type(8))) short bf16x8;   // 8 bf16 = 4 VGPRs
typedef __attribute__((ext_vector_type(4))) float f32x4;
typedef __attribute__((ext_vector_type(2))) float f32x2;    // -> v_pk_*_f32

#if __has_builtin(__builtin_amdgcn_exp2f)
#define EXP2F(x) __builtin_amdgcn_exp2f(x)
#else
#define EXP2F(x) __expf((x) * 0.69314718f)
#endif

#define ALPHA 72.1347520f       // 50 * log2(e)
#define E10   22026.4657948f    // 2^(0.2*ALPHA) = e^10

static __device__ __forceinline__ ushort_t f2bf(float x) {
    unsigned u = __builtin_bit_cast(unsigned, x);
    return (ushort_t)((u + 0x7FFFu + ((u >> 16) & 1u)) >> 16);   // RNE
}
static __device__ __forceinline__ bf16x8 as_frag(int4 v) {
    return __builtin_bit_cast(bf16x8, v);
}

// ------------- kernel 1: L2-normalize -> bf16 (hi only), float4 loads -------------
__global__ __launch_bounds__(256) void knrm_norm(const float* __restrict__ emb,
                                                 ushort_t* __restrict__ nh) {
    int row = blockIdx.x * 8 + (threadIdx.x >> 5);   // V divisible by 8
    int c4  = (threadIdx.x & 31) * 4;
    const float4 v = *reinterpret_cast<const float4*>(emb + (size_t)row * DIM + c4);
    float ss = v.x * v.x + v.y * v.y + v.z * v.z + v.w * v.w;
#pragma unroll
    for (int off = 1; off < 32; off <<= 1) ss += __shfl_xor(ss, off);
    float inv = 1.0f / fmaxf(sqrtf(ss), 1e-12f);
    uint2 o;
    o.x = (unsigned)f2bf(v.x * inv) | ((unsigned)f2bf(v.y * inv) << 16);
    o.y = (unsigned)f2bf(v.z * inv) | ((unsigned)f2bf(v.w * inv) << 16);
    *reinterpret_cast<uint2*>(nh + (size_t)row * DIM + c4) = o;
}

// Two-leg geometric Gaussian bank (verified R6/R9), packed f32x2 (x = leg A,
// kernels 0..9 center mu=-0.5; y = leg B, 10..19 center +0.5), 4 independent
// t*u chains with tree summation. B_j folded in at the partial store.
// Exact kernel (mu=1, sigma=1e-3) = integer token equality count.
// No per-element col mask: RD=200 is 4-aligned, call-site quad guards exact.
static __device__ __forceinline__ void bank4_pk(float4 pv, int4 dt, int qt,
                                                f32x2* ks2, float& cnt) {
    const float mv[4] = {pv.x, pv.y, pv.z, pv.w};
    const int   dv[4] = {dt.x, dt.y, dt.z, dt.w};
    f32x2 t[4], u[4];
#pragma unroll
    for (int i = 0; i < 4; ++i) {
        float m  = mv[i];
        float dA = m + 0.5f, dB = m - 0.5f;
        float tA = EXP2F(-ALPHA * dA * (dA + 0.9f));   // leg A start (k=0)
        float tB = EXP2F(-ALPHA * dB * (dB + 0.9f));   // leg B start (k=10)
        float uB = EXP2F(14.4269504f * dB);            // 2^(0.2*ALPHA*dB)
        float uA = uB * E10;
        t[i] = f32x2{tA, tB};
        u[i] = f32x2{uA, uB};
        cnt += (dv[i] == qt) ? 1.0f : 0.0f;
    }
#pragma unroll
    for (int k = 0; k < 10; ++k) {
        ks2[k] += (t[0] + t[1]) + (t[2] + t[3]);       // tree: short dep chains
        t[0] *= u[0]; t[1] *= u[1]; t[2] *= u[2]; t[3] *= u[3];
    }
}

static __device__ __forceinline__ void load_frag4(const ushort_t* base, int4* f) {
    f[0] = *reinterpret_cast<const int4*>(base);
    f[1] = *reinterpret_cast<const int4*>(base + 32);
    f[2] = *reinterpret_cast<const int4*>(base + 64);
    f[3] = *reinterpret_cast<const int4*>(base + 96);
}

// ------------- kernel 2: single-tile blocks, y=4 col strips -------------
// grid (1024 pair*b, 4 strips of 64 cols), block 256 = 4 waves.
// Per block: one 32x64 M tile. wave = (rt = 16-row tile, half = 32-col half).
// Gather-direct MFMA (no staging LDS), P via LDS (1 barrier), packed
// geometric bank (thread = row x 2 col-quads), partial store per (pb, y).
__global__ __launch_bounds__(256) void knrm_main(
    const ushort_t* __restrict__ nh,
    const int* __restrict__ q1, const int* __restrict__ d1,
    const int* __restrict__ q2, const int* __restrict__ d2,
    float* __restrict__ partial)
{
    __shared__ __align__(16) char smem[10752];
    float (*P)[68] = reinterpret_cast<float (*)[68]>(smem);   // 32x68 f32 = 8704 B
    float* kredw   = reinterpret_cast<float*>(smem);          // 4x32x21 f32 = 10752 B
    __shared__ int sQtok[32];
    __shared__ __align__(16) int sDtok[64];

    const int pb = blockIdx.x, y = blockIdx.y;
    const int pair = pb >> 9, b = pb & 511;
    const int* qind = (pair ? q2 : q1) + b * LQ;
    const int* dind = (pair ? d2 : d1) + b * RD;
    const int cb = y * 64;

    const int tid = threadIdx.x;
    const int lane = tid & 63, wave = tid >> 6;
    const int r = lane & 15, g = lane >> 4;
    const int rt = wave & 1, half = wave >> 1;

    if (tid < 32) sQtok[tid] = (tid < LQ) ? qind[tid] : -2;
    if (tid < 64) { int c = cb + tid; sDtok[tid] = (c < RD) ? dind[c] : -1; }

    // ---- gathers: Q row rt*16+r, D rows cb + half*32 + r / +16 ----
    const int qrow = rt * 16 + r;
    const int qi = qind[qrow < LQ ? qrow : LQ - 1];
    const int dra = cb + half * 32 + r, drb = dra + 16;
    const int dia = dind[dra < RD ? dra : RD - 1];
    const int dib = dind[drb < RD ? drb : RD - 1];

    int4 qh[4], dfa[4], dfb[4];
    load_frag4(nh + (size_t)qi * DIM + g * 8, qh);
    load_frag4(nh + (size_t)dia * DIM + g * 8, dfa);
    load_frag4(nh + (size_t)dib * DIM + g * 8, dfb);

    // ---- 8 MFMAs ----
    f32x4 acc0 = {0.f, 0.f, 0.f, 0.f}, acc1 = {0.f, 0.f, 0.f, 0.f};
#pragma unroll
    for (int ks = 0; ks < 4; ++ks) {
        bf16x8 ah = as_frag(qh[ks]);
        acc0 = __builtin_amdgcn_mfma_f32_16x16x32_bf16(ah, as_frag(dfa[ks]), acc0, 0, 0, 0);
        acc1 = __builtin_amdgcn_mfma_f32_16x16x32_bf16(ah, as_frag(dfb[ks]), acc1, 0, 0, 0);
    }
    // C/D layout: col = lane&15, row = (lane>>4)*4 + j  (m89/m91 verified)
    const int prow0 = rt * 16 + g * 4;
#pragma unroll
    for (int j = 0; j < 4; ++j) {
        P[prow0 + j][half * 32 + r]      = acc0[j];
        P[prow0 + j][half * 32 + 16 + r] = acc1[j];
    }
    __syncthreads();                           // P + tokens visible

    // ---- bank: thread = (row tid&31, quads c0 / c0+32) ----
    const int brow = tid & 31;
    const int c0   = (tid >> 5) * 4;           // 0..28
    f32x2 ks2[10];
#pragma unroll
    for (int k = 0; k < 10; ++k) ks2[k] = f32x2{0.f, 0.f};
    float cnt = 0.0f;

    const int4* sDtok4 = (const int4*)sDtok;
    if (brow < LQ && cb + c0 < RD) {
        const int qt = sQtok[brow];
        float4 p0 = *reinterpret_cast<const float4*>(&P[brow][c0]);
        bank4_pk(p0, sDtok4[c0 >> 2], qt, ks2, cnt);
        if (cb + c0 + 32 < RD) {
            float4 p1 = *reinterpret_cast<const float4*>(&P[brow][c0 + 32]);
            bank4_pk(p1, sDtok4[(c0 + 32) >> 2], qt, ks2, cnt);
        }
    }
    __syncthreads();                           // P dead -> smem = kredw

    // ---- reduce: quad pairs via xor32, cross-wave via LDS ----
#pragma unroll
    for (int k = 0; k < 10; ++k) {
        float va = ks2[k].x + __shfl_xor(ks2[k].x, 32);
        float vb = ks2[k].y + __shfl_xor(ks2[k].y, 32);
        ks2[k] = f32x2{va, vb};
    }
    cnt += __shfl_xor(cnt, 32);
    if (lane < 32) {
        const int base = (wave * 32 + lane) * KN;
#pragma unroll
        for (int k = 0; k < 10; ++k) {
            kredw[base + k]      = ks2[k].x;
            kredw[base + 10 + k] = ks2[k].y;
        }
        kredw[base + 20] = cnt;
    }
    __syncthreads();

    // ---- store partials, folding in the per-kernel B_j constant ----
    float* dst = partial + ((size_t)pb * 4 + y) * (LQ * KN);
    for (int e = tid; e < LQ * KN; e += 256) {
        int row = e / KN, k = e - row * KN;
        float s = kredw[row * KN + k] + kredw[(32 + row) * KN + k]
                + kredw[(64 + row) * KN + k] + kredw[(96 + row) * KN + k];
        float sc = 1.0f;
        if (k < 20) {
            float j = (float)((k < 10) ? k : k - 10) - 4.5f;
            sc = EXP2F(-0.721347520f * j * j);     // B_j = 2^(-0.01*ALPHA*j^2)
        }
        dst[e] = sc * s;
    }
}

// ------------- kernel 3: combine strips, log1p, W-dot, diff, sigmoid -------------
__global__ __launch_bounds__(128) void knrm_finish(const float* __restrict__ partial,
                                                   const float* __restrict__ W,
                                                   float* __restrict__ out) {
    __shared__ float red[2];
    const int b = blockIdx.x, tid = threadIdx.x;
    const float* p1 = partial + (size_t)b * 4 * (LQ * KN);
    const float* p2 = partial + (size_t)(BB + b) * 4 * (LQ * KN);
    float s = 0.0f;
    for (int e = tid; e < LQ * KN; e += 128) {
        int row = e / KN, k = e - row * KN;
        float s1 = p1[e] + p1[LQ * KN + e] + p1[2 * LQ * KN + e] + p1[3 * LQ * KN + e];
        float s2 = p2[e] + p2[LQ * KN + e] + p2[2 * LQ * KN + e] + p2[3 * LQ * KN + e];
        s += W[k] * (log1pf(s1) - log1pf(s2));
    }
#pragma unroll
    for (int off = 1; off < 64; off <<= 1) s += __shfl_xor(s, off);
    if ((tid & 63) == 0) red[tid >> 6] = s;
    __syncthreads();
    if (tid == 0) {
        float logit = red[0] + red[1];   // bias cancels in the difference
        out[b] = 1.0f / (1.0f + expf(-logit));
    }
}

extern "C" void kernel_launch(void* const* d_in, const int* in_sizes, int n_in,
                              void* d_out, int out_size, void* d_ws, size_t ws_size,
                              hipStream_t stream) {
    const float* emb = (const float*)d_in[0];
    const float* W   = (const float*)d_in[1];
    const int* q1    = (const int*)d_in[3];
    const int* dd1   = (const int*)d_in[4];
    const int* q2    = (const int*)d_in[5];
    const int* dd2   = (const int*)d_in[6];

    float* partial = (float*)d_ws;                          // 1024*4*630 f32 = 10.3 MB
    ushort_t* nh   = (ushort_t*)(partial + (size_t)1024 * 4 * LQ * KN);  // 12.8 MB

    knrm_norm<<<V / 8, 256, 0, stream>>>(emb, nh);
    dim3 grid(1024, 4);
    knrm_main<<<grid, 256, 0, stream>>>(nh, q1, dd1, q2, dd2, partial);
    knrm_finish<<<BB, 128, 0, stream>>>(partial, W, (float*)d_out);
}

// Round 12
// 41.079 us; speedup vs baseline: 1.0568x; 1.0568x over previous
//
#include <hip/hip_runtime.h>
#include <math.h>

#define V   50000
#define DIM 128
#define BB  512
#define LQ  30
#define RD  200
#define KN  21

typedef unsigned short ushort_t;
typedef __attribute__((ext_vector_type(8))) short bf16x8;   // 8 bf16 = 4 VGPRs
typedef __attribute__((ext_vector_type(4))) float f32x4;
typedef __attribute__((ext_vector_type(2))) float f32x2;    // -> v_pk_*_f32

#if __has_builtin(__builtin_amdgcn_exp2f)
#define EXP2F(x) __builtin_amdgcn_exp2f(x)
#else
#define EXP2F(x) __expf((x) * 0.69314718f)
#endif

#define ALPHA 72.1347520f       // 50 * log2(e)
#define E10   22026.4657948f    // 2^(0.2*ALPHA) = e^10

static __device__ __forceinline__ ushort_t f2bf(float x) {
    unsigned u = __builtin_bit_cast(unsigned, x);
    return (ushort_t)((u + 0x7FFFu + ((u >> 16) & 1u)) >> 16);   // RNE
}
static __device__ __forceinline__ bf16x8 as_frag(int4 v) {
    return __builtin_bit_cast(bf16x8, v);
}

// ------------- kernel 1: L2-normalize -> bf16 (hi only), float4 loads -------------
__global__ __launch_bounds__(256) void knrm_norm(const float* __restrict__ emb,
                                                 ushort_t* __restrict__ nh) {
    int row = blockIdx.x * 8 + (threadIdx.x >> 5);   // V divisible by 8
    int c4  = (threadIdx.x & 31) * 4;
    const float4 v = *reinterpret_cast<const float4*>(emb + (size_t)row * DIM + c4);
    float ss = v.x * v.x + v.y * v.y + v.z * v.z + v.w * v.w;
#pragma unroll
    for (int off = 1; off < 32; off <<= 1) ss += __shfl_xor(ss, off);
    float inv = 1.0f / fmaxf(sqrtf(ss), 1e-12f);
    uint2 o;
    o.x = (unsigned)f2bf(v.x * inv) | ((unsigned)f2bf(v.y * inv) << 16);
    o.y = (unsigned)f2bf(v.z * inv) | ((unsigned)f2bf(v.w * inv) << 16);
    *reinterpret_cast<uint2*>(nh + (size_t)row * DIM + c4) = o;
}

// Two-leg geometric Gaussian bank (verified R6/R9), packed f32x2 (x = leg A,
// kernels 0..9 center mu=-0.5; y = leg B, 10..19 center +0.5), 4 independent
// t*u chains, tree summation. B_j folded in at the combine stage.
// Exact kernel (mu=1, sigma=1e-3) = integer token equality count.
static __device__ __forceinline__ void bank4_pk(f32x4 pv, int4 dt, int qt,
                                                f32x2* ks2, float& cnt) {
    const float mv[4] = {pv[0], pv[1], pv[2], pv[3]};
    const int   dv[4] = {dt.x, dt.y, dt.z, dt.w};
    f32x2 t[4], u[4];
#pragma unroll
    for (int i = 0; i < 4; ++i) {
        float m  = mv[i];
        float dA = m + 0.5f, dB = m - 0.5f;
        float tA = EXP2F(-ALPHA * dA * (dA + 0.9f));   // leg A start (k=0)
        float tB = EXP2F(-ALPHA * dB * (dB + 0.9f));   // leg B start (k=10)
        float uB = EXP2F(14.4269504f * dB);            // 2^(0.2*ALPHA*dB)
        float uA = uB * E10;
        t[i] = f32x2{tA, tB};
        u[i] = f32x2{uA, uB};
        cnt += (dv[i] == qt) ? 1.0f : 0.0f;
    }
#pragma unroll
    for (int k = 0; k < 10; ++k) {
        ks2[k] += (t[0] + t[1]) + (t[2] + t[3]);       // tree: short dep chains
        t[0] *= u[0]; t[1] *= u[1]; t[2] *= u[2]; t[3] *= u[3];
    }
}

static __device__ __forceinline__ void load_frag4(const ushort_t* base, int4* f) {
    f[0] = *reinterpret_cast<const int4*>(base);
    f[1] = *reinterpret_cast<const int4*>(base + 32);
    f[2] = *reinterpret_cast<const int4*>(base + 64);
    f[3] = *reinterpret_cast<const int4*>(base + 96);
}

// ------------- kernel 2: swapped-operand register-direct KNRM, in-block finish -------
// 1024 blocks (pair*b) x 256 thr (4 waves). Wave w owns doc cols w*64..w*64+63
// (4 strips of 16; wave 3: 1 strip, RD=200). mfma(A=D_frag, B=Q_frag):
// C row = dcol (g*4+j), C col = qrow (r) -> bank consumes accumulators
// directly from registers; no P tile, no partial buffer, combine in-block.
__global__ __launch_bounds__(256, 4) void knrm_main(
    const ushort_t* __restrict__ nh, const float* __restrict__ W,
    const int* __restrict__ q1, const int* __restrict__ d1,
    const int* __restrict__ q2, const int* __restrict__ d2,
    float* __restrict__ logits)
{
    __shared__ int sQtok[32];
    __shared__ __align__(16) int sDtok[256];
    __shared__ float kred[4][32][KN];              // 10752 B

    const int pb = blockIdx.x;
    const int pair = pb >> 9, b = pb & 511;
    const int* qind = (pair ? q2 : q1) + b * LQ;
    const int* dind = (pair ? d2 : d1) + b * RD;

    const int tid = threadIdx.x;
    const int lane = tid & 63, w = tid >> 6;
    const int r = lane & 15, g = lane >> 4;

    if (tid < 32) sQtok[tid] = (tid < LQ) ? qind[tid] : -2;
    { int c = tid; sDtok[c] = (c < RD) ? dind[c] : -1; }

    // ---- Q frags (B operand): rowgroup A = rows 0..15, B = 16..31 (clamped) ----
    const int qiA = qind[r];
    const int qiB = qind[(16 + r) < LQ ? (16 + r) : LQ - 1];
    int4 qa[4], qb[4];
    load_frag4(nh + (size_t)qiA * DIM + g * 8, qa);
    load_frag4(nh + (size_t)qiB * DIM + g * 8, qb);

    __syncthreads();                               // token tables ready

    const int qt0 = sQtok[r], qt1 = sQtok[16 + r];
    const int4* sDtok4 = (const int4*)sDtok;

    f32x2 ks0[10], ks1[10];
#pragma unroll
    for (int k = 0; k < 10; ++k) { ks0[k] = f32x2{0.f, 0.f}; ks1[k] = f32x2{0.f, 0.f}; }
    float cnt0 = 0.0f, cnt1 = 0.0f;

    const int ns = (w < 3) ? 4 : 1;                // strips this wave runs
#pragma unroll 2
    for (int s = 0; s < ns; ++s) {
        const int sbase = w * 64 + s * 16;
        const int dcol = sbase + r;
        const int di = sDtok[dcol < RD ? dcol : RD - 1];

        int4 df[4];
        load_frag4(nh + (size_t)di * DIM + g * 8, df);

        f32x4 acc0 = {0.f, 0.f, 0.f, 0.f}, acc1 = {0.f, 0.f, 0.f, 0.f};
#pragma unroll
        for (int ks = 0; ks < 4; ++ks) {
            bf16x8 fd = as_frag(df[ks]);
            acc0 = __builtin_amdgcn_mfma_f32_16x16x32_bf16(fd, as_frag(qa[ks]), acc0, 0, 0, 0);
            acc1 = __builtin_amdgcn_mfma_f32_16x16x32_bf16(fd, as_frag(qb[ks]), acc1, 0, 0, 0);
        }

        // acc element j <-> dcol = sbase + g*4 + j ; qrow = r (+16 for acc1)
        if (sbase + g * 4 < RD) {                  // RD%4==0 -> quad all-or-none
            const int4 dt = sDtok4[(sbase >> 2) + g];
            bank4_pk(acc0, dt, qt0, ks0, cnt0);
            bank4_pk(acc1, dt, qt1, ks1, cnt1);
        }
    }

    // ---- reduce over g (xor16, xor32), writer lanes g==0 ----
#pragma unroll
    for (int k = 0; k < 10; ++k) {
        float a0 = ks0[k].x, b0 = ks0[k].y, a1 = ks1[k].x, b1 = ks1[k].y;
        a0 += __shfl_xor(a0, 16); a0 += __shfl_xor(a0, 32);
        b0 += __shfl_xor(b0, 16); b0 += __shfl_xor(b0, 32);
        a1 += __shfl_xor(a1, 16); a1 += __shfl_xor(a1, 32);
        b1 += __shfl_xor(b1, 16); b1 += __shfl_xor(b1, 32);
        ks0[k] = f32x2{a0, b0};
        ks1[k] = f32x2{a1, b1};
    }
    cnt0 += __shfl_xor(cnt0, 16); cnt0 += __shfl_xor(cnt0, 32);
    cnt1 += __shfl_xor(cnt1, 16); cnt1 += __shfl_xor(cnt1, 32);

    if (lane < 16) {
        float* k0 = &kred[w][r][0];
        float* k1 = &kred[w][16 + r][0];
#pragma unroll
        for (int k = 0; k < 10; ++k) {
            k0[k] = ks0[k].x;  k0[10 + k] = ks0[k].y;
            k1[k] = ks1[k].x;  k1[10 + k] = ks1[k].y;
        }
        k0[20] = cnt0;
        k1[20] = cnt1;
    }
    __syncthreads();

    // ---- in-block combine: B_j scale, log1p, W-dot, row reduce -> logit ----
    if (lane < 32 && tid < 64) { /* wave 0 handles it */ }
    if (tid < 64) {
        float part = 0.0f;
        if (tid < LQ) {
#pragma unroll
            for (int k = 0; k < KN; ++k) {
                float s = kred[0][tid][k] + kred[1][tid][k]
                        + kred[2][tid][k] + kred[3][tid][k];
                float sc = 1.0f;
                if (k < 20) {
                    float j = (float)((k < 10) ? k : k - 10) - 4.5f;
                    sc = EXP2F(-0.721347520f * j * j);   // B_j (compile-time)
                }
                part += W[k] * log1pf(sc * s);
            }
        }
        part += __shfl_xor(part, 1);
        part += __shfl_xor(part, 2);
        part += __shfl_xor(part, 4);
        part += __shfl_xor(part, 8);
        part += __shfl_xor(part, 16);
        part += __shfl_xor(part, 32);
        if (tid == 0) logits[pair * BB + b] = part;   // bias cancels in diff
    }
}

// ------------- kernel 3: sigmoid of logit difference -------------
__global__ void knrm_final(const float* __restrict__ logits, float* __restrict__ out) {
    int i = blockIdx.x * blockDim.x + threadIdx.x;
    if (i < BB) {
        float x = logits[i] - logits[BB + i];
        out[i] = 1.0f / (1.0f + expf(-x));
    }
}

extern "C" void kernel_launch(void* const* d_in, const int* in_sizes, int n_in,
                              void* d_out, int out_size, void* d_ws, size_t ws_size,
                              hipStream_t stream) {
    const float* emb = (const float*)d_in[0];
    const float* W   = (const float*)d_in[1];
    const int* q1    = (const int*)d_in[3];
    const int* dd1   = (const int*)d_in[4];
    const int* q2    = (const int*)d_in[5];
    const int* dd2   = (const int*)d_in[6];

    ushort_t* nh  = (ushort_t*)d_ws;                 // V*128 bf16 = 12.8 MB
    float* logits = (float*)(nh + (size_t)V * DIM);  // 1024 floats

    knrm_norm<<<V / 8, 256, 0, stream>>>(emb, nh);
    knrm_main<<<1024, 256, 0, stream>>>(nh, W, q1, dd1, q2, dd2, logits);
    knrm_final<<<2, 256, 0, stream>>>(logits, (float*)d_out);
}

// Round 13
// 38.233 us; speedup vs baseline: 1.1355x; 1.0744x over previous
//
#include <hip/hip_runtime.h>
#include <hip/hip_fp16.h>
#include <math.h>

#define V   50000
#define DIM 128
#define BB  512
#define LQ  30
#define RD  200
#define KN  21

typedef __attribute__((ext_vector_type(8))) _Float16 f16x8;  // 8 f16 = 4 VGPRs
typedef __attribute__((ext_vector_type(4))) float f32x4;
typedef __attribute__((ext_vector_type(2))) float f32x2;     // -> v_pk_*_f32

#if __has_builtin(__builtin_amdgcn_exp2f)
#define EXP2F(x) __builtin_amdgcn_exp2f(x)
#else
#define EXP2F(x) __expf((x) * 0.69314718f)
#endif

#define ALPHA 72.1347520f       // 50 * log2(e)
#define E10   22026.4657948f    // 2^(0.2*ALPHA) = e^10

static __device__ __forceinline__ f16x8 as_hfrag(int4 v) {
    return __builtin_bit_cast(f16x8, v);
}
static __device__ __forceinline__ unsigned pk2h(float a, float b) {
    return __builtin_bit_cast(unsigned, __builtin_amdgcn_cvt_pkrtz(a, b));
}
static __device__ __forceinline__ unsigned hscale(unsigned u, __half2 s) {
    return __builtin_bit_cast(unsigned, __hmul2(__builtin_bit_cast(__half2, u), s));
}

// Fused gather+normalize+f16-convert of one embedding row.
// Lanes (r, g=0..3) jointly hold the row; lane slice = elements ks*32+g*8..+7.
// ss reduced across g via shfl_xor 16/32 (same-row lanes differ only in g).
// Convert RTZ unscaled first (frees f32 regs), then scale by inv-norm in f16.
static __device__ __forceinline__ void gather_row_f16(const float* __restrict__ rowp,
                                                      int g, int4* f) {
    float ss = 0.0f;
#pragma unroll
    for (int ks = 0; ks < 4; ++ks) {
        const float4* p = reinterpret_cast<const float4*>(rowp + ks * 32 + g * 8);
        float4 a = p[0], b = p[1];
        ss = fmaf(a.x, a.x, fmaf(a.y, a.y, fmaf(a.z, a.z, fmaf(a.w, a.w, ss))));
        ss = fmaf(b.x, b.x, fmaf(b.y, b.y, fmaf(b.z, b.z, fmaf(b.w, b.w, ss))));
        f[ks].x = (int)pk2h(a.x, a.y);
        f[ks].y = (int)pk2h(a.z, a.w);
        f[ks].z = (int)pk2h(b.x, b.y);
        f[ks].w = (int)pk2h(b.z, b.w);
    }
    ss += __shfl_xor(ss, 16);
    ss += __shfl_xor(ss, 32);
    const float inv = rsqrtf(fmaxf(ss, 1e-24f));
    const __half2 h2 = __float2half2_rn(inv);
#pragma unroll
    for (int ks = 0; ks < 4; ++ks) {
        f[ks].x = (int)hscale((unsigned)f[ks].x, h2);
        f[ks].y = (int)hscale((unsigned)f[ks].y, h2);
        f[ks].z = (int)hscale((unsigned)f[ks].z, h2);
        f[ks].w = (int)hscale((unsigned)f[ks].w, h2);
    }
}

// Two-leg geometric Gaussian bank (verified R6/R9/R12), packed f32x2
// (x = leg A, kernels 0..9 center mu=-0.5; y = leg B, 10..19 center +0.5),
// 4 independent t*u chains, tree summation. B_j folded in at combine.
// Exact kernel (mu=1, sigma=1e-3) = integer token equality count.
static __device__ __forceinline__ void bank4_pk(f32x4 pv, int4 dt, int qt,
                                                f32x2* ks2, float& cnt) {
    const float mv[4] = {pv[0], pv[1], pv[2], pv[3]};
    const int   dv[4] = {dt.x, dt.y, dt.z, dt.w};
    f32x2 t[4], u[4];
#pragma unroll
    for (int i = 0; i < 4; ++i) {
        float m  = mv[i];
        float dA = m + 0.5f, dB = m - 0.5f;
        float tA = EXP2F(-ALPHA * dA * (dA + 0.9f));   // leg A start (k=0)
        float tB = EXP2F(-ALPHA * dB * (dB + 0.9f));   // leg B start (k=10)
        float uB = EXP2F(14.4269504f * dB);            // 2^(0.2*ALPHA*dB)
        float uA = uB * E10;
        t[i] = f32x2{tA, tB};
        u[i] = f32x2{uA, uB};
        cnt += (dv[i] == qt) ? 1.0f : 0.0f;
    }
#pragma unroll
    for (int k = 0; k < 10; ++k) {
        ks2[k] += (t[0] + t[1]) + (t[2] + t[3]);       // tree: short dep chains
        t[0] *= u[0]; t[1] *= u[1]; t[2] *= u[2]; t[3] *= u[3];
    }
}

// ------------- kernel: fused normalize + swapped-operand register-direct KNRM -------
// 1024 blocks (pair*b) x 256 thr (4 waves). Wave w owns doc cols w*64..w*64+63
// (4 strips of 16; wave 3: 1 strip, RD=200). mfma(A=D_frag, B=Q_frag):
// C row = dcol (g*4+j), C col = qrow (r) -> bank consumes accumulators
// directly from registers. No pre-pass: rows normalized+f16-converted on gather.
__global__ __launch_bounds__(256, 4) void knrm_main(
    const float* __restrict__ emb, const float* __restrict__ W,
    const int* __restrict__ q1, const int* __restrict__ d1,
    const int* __restrict__ q2, const int* __restrict__ d2,
    float* __restrict__ logits)
{
    __shared__ int sQtok[32];
    __shared__ __align__(16) int sDtok[256];
    __shared__ float kred[4][32][KN];              // 10752 B

    const int pb = blockIdx.x;
    const int pair = pb >> 9, b = pb & 511;
    const int* qind = (pair ? q2 : q1) + b * LQ;
    const int* dind = (pair ? d2 : d1) + b * RD;

    const int tid = threadIdx.x;
    const int lane = tid & 63, w = tid >> 6;
    const int r = lane & 15, g = lane >> 4;

    if (tid < 32) sQtok[tid] = (tid < LQ) ? qind[tid] : -2;
    { int c = tid; sDtok[c] = (c < RD) ? dind[c] : -1; }

    // ---- Q frags (B operand): rowgroup A = rows 0..15, B = 16..31 (clamped) ----
    const int qiA = qind[r];
    const int qiB = qind[(16 + r) < LQ ? (16 + r) : LQ - 1];
    int4 qa[4], qb[4];
    gather_row_f16(emb + (size_t)qiA * DIM, g, qa);
    gather_row_f16(emb + (size_t)qiB * DIM, g, qb);

    __syncthreads();                               // token tables ready

    const int qt0 = sQtok[r], qt1 = sQtok[16 + r];
    const int4* sDtok4 = (const int4*)sDtok;

    f32x2 ks0[10], ks1[10];
#pragma unroll
    for (int k = 0; k < 10; ++k) { ks0[k] = f32x2{0.f, 0.f}; ks1[k] = f32x2{0.f, 0.f}; }
    float cnt0 = 0.0f, cnt1 = 0.0f;

    const int ns = (w < 3) ? 4 : 1;                // strips this wave runs
#pragma unroll 2
    for (int s = 0; s < ns; ++s) {
        const int sbase = w * 64 + s * 16;
        const int dcol = sbase + r;
        const int di = sDtok[dcol < RD ? dcol : RD - 1];

        int4 df[4];
        gather_row_f16(emb + (size_t)di * DIM, g, df);

        f32x4 acc0 = {0.f, 0.f, 0.f, 0.f}, acc1 = {0.f, 0.f, 0.f, 0.f};
#pragma unroll
        for (int ks = 0; ks < 4; ++ks) {
            f16x8 fd = as_hfrag(df[ks]);
            acc0 = __builtin_amdgcn_mfma_f32_16x16x32_f16(fd, as_hfrag(qa[ks]), acc0, 0, 0, 0);
            acc1 = __builtin_amdgcn_mfma_f32_16x16x32_f16(fd, as_hfrag(qb[ks]), acc1, 0, 0, 0);
        }

        // acc element j <-> dcol = sbase + g*4 + j ; qrow = r (+16 for acc1)
        if (sbase + g * 4 < RD) {                  // RD%4==0 -> quad all-or-none
            const int4 dt = sDtok4[(sbase >> 2) + g];
            bank4_pk(acc0, dt, qt0, ks0, cnt0);
            bank4_pk(acc1, dt, qt1, ks1, cnt1);
        }
    }

    // ---- reduce over g (xor16, xor32), writer lanes g==0 ----
#pragma unroll
    for (int k = 0; k < 10; ++k) {
        float a0 = ks0[k].x, b0 = ks0[k].y, a1 = ks1[k].x, b1 = ks1[k].y;
        a0 += __shfl_xor(a0, 16); a0 += __shfl_xor(a0, 32);
        b0 += __shfl_xor(b0, 16); b0 += __shfl_xor(b0, 32);
        a1 += __shfl_xor(a1, 16); a1 += __shfl_xor(a1, 32);
        b1 += __shfl_xor(b1, 16); b1 += __shfl_xor(b1, 32);
        ks0[k] = f32x2{a0, b0};
        ks1[k] = f32x2{a1, b1};
    }
    cnt0 += __shfl_xor(cnt0, 16); cnt0 += __shfl_xor(cnt0, 32);
    cnt1 += __shfl_xor(cnt1, 16); cnt1 += __shfl_xor(cnt1, 32);

    if (lane < 16) {
        float* k0 = &kred[w][r][0];
        float* k1 = &kred[w][16 + r][0];
#pragma unroll
        for (int k = 0; k < 10; ++k) {
            k0[k] = ks0[k].x;  k0[10 + k] = ks0[k].y;
            k1[k] = ks1[k].x;  k1[10 + k] = ks1[k].y;
        }
        k0[20] = cnt0;
        k1[20] = cnt1;
    }
    __syncthreads();

    // ---- in-block combine: B_j scale, log1p, W-dot, row reduce -> logit ----
    if (tid < 64) {
        float part = 0.0f;
        if (tid < LQ) {
#pragma unroll
            for (int k = 0; k < KN; ++k) {
                float s = kred[0][tid][k] + kred[1][tid][k]
                        + kred[2][tid][k] + kred[3][tid][k];
                float sc = 1.0f;
                if (k < 20) {
                    float j = (float)((k < 10) ? k : k - 10) - 4.5f;
                    sc = EXP2F(-0.721347520f * j * j);   // B_j (compile-time)
                }
                part += W[k] * log1pf(sc * s);
            }
        }
        part += __shfl_xor(part, 1);
        part += __shfl_xor(part, 2);
        part += __shfl_xor(part, 4);
        part += __shfl_xor(part, 8);
        part += __shfl_xor(part, 16);
        part += __shfl_xor(part, 32);
        if (tid == 0) logits[pair * BB + b] = part;   // bias cancels in diff
    }
}

// ------------- kernel 2: sigmoid of logit difference -------------
__global__ void knrm_final(const float* __restrict__ logits, float* __restrict__ out) {
    int i = blockIdx.x * blockDim.x + threadIdx.x;
    if (i < BB) {
        float x = logits[i] - logits[BB + i];
        out[i] = 1.0f / (1.0f + expf(-x));
    }
}

extern "C" void kernel_launch(void* const* d_in, const int* in_sizes, int n_in,
                              void* d_out, int out_size, void* d_ws, size_t ws_size,
                              hipStream_t stream) {
    const float* emb = (const float*)d_in[0];
    const float* W   = (const float*)d_in[1];
    const int* q1    = (const int*)d_in[3];
    const int* dd1   = (const int*)d_in[4];
    const int* q2    = (const int*)d_in[5];
    const int* dd2   = (const int*)d_in[6];

    float* logits = (float*)d_ws;                    // 1024 floats

    knrm_main<<<1024, 256, 0, stream>>>(emb, W, q1, dd1, q2, dd2, logits);
    knrm_final<<<2, 256, 0, stream>>>(logits, (float*)d_out);
}

// Round 14
// 33.978 us; speedup vs baseline: 1.2776x; 1.1252x over previous
//
#include <hip/hip_runtime.h>
#include <hip/hip_fp16.h>
#include <math.h>

#define V   50000
#define DIM 128
#define BB  512
#define LQ  30
#define RD  200
#define KN  21

typedef __attribute__((ext_vector_type(8))) _Float16 f16x8;  // 8 f16 = 4 VGPRs
typedef __attribute__((ext_vector_type(4))) float f32x4;
typedef __attribute__((ext_vector_type(2))) float f32x2;     // -> v_pk_*_f32

#if __has_builtin(__builtin_amdgcn_exp2f)
#define EXP2F(x) __builtin_amdgcn_exp2f(x)
#else
#define EXP2F(x) __expf((x) * 0.69314718f)
#endif

#define ALPHA 72.1347520f       // 50 * log2(e)
#define E10   22026.4657948f    // 2^(0.2*ALPHA) = e^10

static __device__ __forceinline__ f16x8 as_hfrag(int4 v) {
    return __builtin_bit_cast(f16x8, v);
}
static __device__ __forceinline__ unsigned pk2h(float a, float b) {
    return __builtin_bit_cast(unsigned, __builtin_amdgcn_cvt_pkrtz(a, b));
}
static __device__ __forceinline__ unsigned hscale(unsigned u, __half2 s) {
    return __builtin_bit_cast(unsigned, __hmul2(__builtin_bit_cast(__half2, u), s));
}

// Fused gather+normalize+f16-convert of one embedding row (doc side).
// Lanes (r, g=0..3) jointly hold the row; lane slice = elements ks*32+g*8..+7.
// ss reduced across g via shfl_xor 16/32. RTZ-pack first, then f16 scale.
static __device__ __forceinline__ void gather_row_f16(const float* __restrict__ rowp,
                                                      int g, int4* f) {
    float ss = 0.0f;
#pragma unroll
    for (int ks = 0; ks < 4; ++ks) {
        const float4* p = reinterpret_cast<const float4*>(rowp + ks * 32 + g * 8);
        float4 a = p[0], b = p[1];
        ss = fmaf(a.x, a.x, fmaf(a.y, a.y, fmaf(a.z, a.z, fmaf(a.w, a.w, ss))));
        ss = fmaf(b.x, b.x, fmaf(b.y, b.y, fmaf(b.z, b.z, fmaf(b.w, b.w, ss))));
        f[ks].x = (int)pk2h(a.x, a.y);
        f[ks].y = (int)pk2h(a.z, a.w);
        f[ks].z = (int)pk2h(b.x, b.y);
        f[ks].w = (int)pk2h(b.z, b.w);
    }
    ss += __shfl_xor(ss, 16);
    ss += __shfl_xor(ss, 32);
    const float inv = rsqrtf(fmaxf(ss, 1e-24f));
    const __half2 h2 = __float2half2_rn(inv);
#pragma unroll
    for (int ks = 0; ks < 4; ++ks) {
        f[ks].x = (int)hscale((unsigned)f[ks].x, h2);
        f[ks].y = (int)hscale((unsigned)f[ks].y, h2);
        f[ks].z = (int)hscale((unsigned)f[ks].z, h2);
        f[ks].w = (int)hscale((unsigned)f[ks].w, h2);
    }
}

// Two-leg geometric Gaussian bank (verified R6/R9/R12/R13), packed f32x2
// (x = leg A, kernels 0..9 center mu=-0.5; y = leg B, 10..19 center +0.5),
// 4 independent t*u chains, tree summation. B_j folded in at combine.
// Exact kernel (mu=1, sigma=1e-3) = integer token equality count.
static __device__ __forceinline__ void bank4_pk(f32x4 pv, int4 dt, int qt,
                                                f32x2* ks2, float& cnt) {
    const float mv[4] = {pv[0], pv[1], pv[2], pv[3]};
    const int   dv[4] = {dt.x, dt.y, dt.z, dt.w};
    f32x2 t[4], u[4];
#pragma unroll
    for (int i = 0; i < 4; ++i) {
        float m  = mv[i];
        float dA = m + 0.5f, dB = m - 0.5f;
        float tA = EXP2F(-ALPHA * dA * (dA + 0.9f));   // leg A start (k=0)
        float tB = EXP2F(-ALPHA * dB * (dB + 0.9f));   // leg B start (k=10)
        float uB = EXP2F(14.4269504f * dB);            // 2^(0.2*ALPHA*dB)
        float uA = uB * E10;
        t[i] = f32x2{tA, tB};
        u[i] = f32x2{uA, uB};
        cnt += (dv[i] == qt) ? 1.0f : 0.0f;
    }
#pragma unroll
    for (int k = 0; k < 10; ++k) {
        ks2[k] += (t[0] + t[1]) + (t[2] + t[3]);       // tree: short dep chains
        t[0] *= u[0]; t[1] *= u[1]; t[2] *= u[2]; t[3] *= u[3];
    }
}

// ------------- kernel: fused-norm swapped-operand KNRM, cooperative Q staging -------
// 1024 blocks (pair*b) x 256 thr (4 waves). Wave w owns doc cols w*64..+63
// (4 strips of 16; wave 3: 1 strip). mfma(A=D_frag, B=Q_frag): C row = dcol
// (g*4+j), C col = qrow (r) -> bank consumes accumulators from registers.
// Q rows normalized ONCE per block into an XOR-swizzled 8KB LDS f16 tile
// (was: re-gathered+re-normalized by all 4 waves). Doc rows fused-gathered.
__global__ __launch_bounds__(256, 4) void knrm_main(
    const float* __restrict__ emb, const float* __restrict__ W,
    const int* __restrict__ q1, const int* __restrict__ d1,
    const int* __restrict__ q2, const int* __restrict__ d2,
    float* __restrict__ logits)
{
    __shared__ int sQtok[32];
    __shared__ __align__(16) int sDtok[256];
    __shared__ int4 sQ[32][16];                    // 32 rows x 256B f16, swizzled
    __shared__ float kred[4][32][KN];              // 10752 B

    const int pb = blockIdx.x;
    const int pair = pb >> 9, b = pb & 511;
    const int* qind = (pair ? q2 : q1) + b * LQ;
    const int* dind = (pair ? d2 : d1) + b * RD;

    const int tid = threadIdx.x;
    const int lane = tid & 63, w = tid >> 6;
    const int r = lane & 15, g = lane >> 4;

    if (tid < 32) sQtok[tid] = (tid < LQ) ? qind[tid] : -2;
    // clamped padding tokens: padded quads never reach the bank (quad guard),
    // so no -1 sentinel needed -> no clamp select on the strip address path
    sDtok[tid] = dind[tid < RD ? tid : RD - 1];

    // ---- cooperative Q staging: row = tid>>3, 16 elems per thread ----
    {
        const int row = tid >> 3, seg = tid & 7;
        const int qi = qind[row < LQ ? row : LQ - 1];
        const float4* p = reinterpret_cast<const float4*>(emb + (size_t)qi * DIM + seg * 16);
        float4 v0 = p[0], v1 = p[1], v2 = p[2], v3 = p[3];
        float ss = 0.0f;
        ss = fmaf(v0.x, v0.x, fmaf(v0.y, v0.y, fmaf(v0.z, v0.z, fmaf(v0.w, v0.w, ss))));
        ss = fmaf(v1.x, v1.x, fmaf(v1.y, v1.y, fmaf(v1.z, v1.z, fmaf(v1.w, v1.w, ss))));
        ss = fmaf(v2.x, v2.x, fmaf(v2.y, v2.y, fmaf(v2.z, v2.z, fmaf(v2.w, v2.w, ss))));
        ss = fmaf(v3.x, v3.x, fmaf(v3.y, v3.y, fmaf(v3.z, v3.z, fmaf(v3.w, v3.w, ss))));
        ss += __shfl_xor(ss, 1);
        ss += __shfl_xor(ss, 2);
        ss += __shfl_xor(ss, 4);
        const float inv = rsqrtf(fmaxf(ss, 1e-24f));
        int4 s0, s1;
        s0.x = (int)pk2h(v0.x * inv, v0.y * inv);
        s0.y = (int)pk2h(v0.z * inv, v0.w * inv);
        s0.z = (int)pk2h(v1.x * inv, v1.y * inv);
        s0.w = (int)pk2h(v1.z * inv, v1.w * inv);
        s1.x = (int)pk2h(v2.x * inv, v2.y * inv);
        s1.y = (int)pk2h(v2.z * inv, v2.w * inv);
        s1.z = (int)pk2h(v3.x * inv, v3.y * inv);
        s1.w = (int)pk2h(v3.z * inv, v3.w * inv);
        const int rw = row & 15;                   // XOR-swizzle (rule 21: both sides)
        sQ[row][(2 * seg) ^ rw]     = s0;
        sQ[row][(2 * seg + 1) ^ rw] = s1;
    }
    __syncthreads();                               // tokens + sQ ready (only barrier)

    // ---- Q frags from LDS (swizzled read, conflict-free) ----
    int4 qa[4], qb[4];
#pragma unroll
    for (int ks = 0; ks < 4; ++ks) {
        qa[ks] = sQ[r][(ks * 4 + g) ^ r];
        qb[ks] = sQ[16 + r][(ks * 4 + g) ^ r];
    }
    const int qt0 = sQtok[r], qt1 = sQtok[16 + r];
    const int4* sDtok4 = (const int4*)sDtok;

    f32x2 ks0[10], ks1[10];
#pragma unroll
    for (int k = 0; k < 10; ++k) { ks0[k] = f32x2{0.f, 0.f}; ks1[k] = f32x2{0.f, 0.f}; }
    float cnt0 = 0.0f, cnt1 = 0.0f;

    auto strip = [&](int sbase) {
        const int di = sDtok[sbase + r];
        int4 df[4];
        gather_row_f16(emb + (size_t)di * DIM, g, df);
        f32x4 acc0 = {0.f, 0.f, 0.f, 0.f}, acc1 = {0.f, 0.f, 0.f, 0.f};
#pragma unroll
        for (int ks = 0; ks < 4; ++ks) {
            f16x8 fd = as_hfrag(df[ks]);
            acc0 = __builtin_amdgcn_mfma_f32_16x16x32_f16(fd, as_hfrag(qa[ks]), acc0, 0, 0, 0);
            acc1 = __builtin_amdgcn_mfma_f32_16x16x32_f16(fd, as_hfrag(qb[ks]), acc1, 0, 0, 0);
        }
        // acc element j <-> dcol = sbase + g*4 + j ; qrow = r (+16 for acc1)
        if (sbase + g * 4 < RD) {                  // RD%4==0 -> quad all-or-none
            const int4 dt = sDtok4[(sbase >> 2) + g];
            bank4_pk(acc0, dt, qt0, ks0, cnt0);
            bank4_pk(acc1, dt, qt1, ks1, cnt1);
        }
    };

    if (w < 3) {
#pragma unroll 2
        for (int s = 0; s < 4; ++s) strip(w * 64 + s * 16);
    } else {
        strip(192);
    }

    // ---- reduce over g (xor16, xor32), writer lanes g==0 ----
#pragma unroll
    for (int k = 0; k < 10; ++k) {
        float a0 = ks0[k].x, b0 = ks0[k].y, a1 = ks1[k].x, b1 = ks1[k].y;
        a0 += __shfl_xor(a0, 16); a0 += __shfl_xor(a0, 32);
        b0 += __shfl_xor(b0, 16); b0 += __shfl_xor(b0, 32);
        a1 += __shfl_xor(a1, 16); a1 += __shfl_xor(a1, 32);
        b1 += __shfl_xor(b1, 16); b1 += __shfl_xor(b1, 32);
        ks0[k] = f32x2{a0, b0};
        ks1[k] = f32x2{a1, b1};
    }
    cnt0 += __shfl_xor(cnt0, 16); cnt0 += __shfl_xor(cnt0, 32);
    cnt1 += __shfl_xor(cnt1, 16); cnt1 += __shfl_xor(cnt1, 32);

    if (lane < 16) {
        float* k0 = &kred[w][r][0];
        float* k1 = &kred[w][16 + r][0];
#pragma unroll
        for (int k = 0; k < 10; ++k) {
            k0[k] = ks0[k].x;  k0[10 + k] = ks0[k].y;
            k1[k] = ks1[k].x;  k1[10 + k] = ks1[k].y;
        }
        k0[20] = cnt0;
        k1[20] = cnt1;
    }
    __syncthreads();

    // ---- in-block combine: B_j scale, log1p, W-dot, row reduce -> logit ----
    if (tid < 64) {
        float part = 0.0f;
        if (tid < LQ) {
#pragma unroll
            for (int k = 0; k < KN; ++k) {
                float s = kred[0][tid][k] + kred[1][tid][k]
                        + kred[2][tid][k] + kred[3][tid][k];
                float sc = 1.0f;
                if (k < 20) {
                    float j = (float)((k < 10) ? k : k - 10) - 4.5f;
                    sc = EXP2F(-0.721347520f * j * j);   // B_j (compile-time)
                }
                part += W[k] * log1pf(sc * s);
            }
        }
        part += __shfl_xor(part, 1);
        part += __shfl_xor(part, 2);
        part += __shfl_xor(part, 4);
        part += __shfl_xor(part, 8);
        part += __shfl_xor(part, 16);
        part += __shfl_xor(part, 32);
        if (tid == 0) logits[pair * BB + b] = part;   // bias cancels in diff
    }
}

// ------------- kernel 2: sigmoid of logit difference -------------
__global__ void knrm_final(const float* __restrict__ logits, float* __restrict__ out) {
    int i = blockIdx.x * blockDim.x + threadIdx.x;
    if (i < BB) {
        float x = logits[i] - logits[BB + i];
        out[i] = 1.0f / (1.0f + expf(-x));
    }
}

extern "C" void kernel_launch(void* const* d_in, const int* in_sizes, int n_in,
                              void* d_out, int out_size, void* d_ws, size_t ws_size,
                              hipStream_t stream) {
    const float* emb = (const float*)d_in[0];
    const float* W   = (const float*)d_in[1];
    const int* q1    = (const int*)d_in[3];
    const int* dd1   = (const int*)d_in[4];
    const int* q2    = (const int*)d_in[5];
    const int* dd2   = (const int*)d_in[6];

    float* logits = (float*)d_ws;                    // 1024 floats

    knrm_main<<<1024, 256, 0, stream>>>(emb, W, q1, dd1, q2, dd2, logits);
    knrm_final<<<2, 256, 0, stream>>>(logits, (float*)d_out);
}